// Round 4
// 217.778 us; speedup vs baseline: 1.0412x; 1.0412x over previous
//
#include <hip/hip_runtime.h>
#include <hip/hip_bf16.h>

// Problem: B=16, C=512, H=W=32 (N=1024), 32 groups (16 ch/group).
// Wire dtype: fp32; internal GEMM dtype: bf16.
// R9 resubmit (R9 bench was an infra failure -- container died twice, kernel
//   never evaluated). Structure: known-good R6 + XCD-chunked block swizzle
//   (T1) on the 4 GEMM kernels -- a provably bijective blockIdx->tile
//   relabeling (all GEMM grids % 8 == 0) so each XCD's private 4MB L2 sees a
//   contiguous tile chunk and shared operand panels stop being re-fetched by
//   all 8 XCDs. Zero semantic / sync / LDS delta vs R6.

typedef __attribute__((ext_vector_type(8))) short bf16x8;   // 8 bf16 = 4 VGPRs
typedef __attribute__((ext_vector_type(4))) float f32x4;

__device__ __forceinline__ float b2f(ushort u) {
  unsigned int v = ((unsigned int)u) << 16;
  float f; __builtin_memcpy(&f, &v, 4); return f;
}
__device__ __forceinline__ ushort f2b(float f) {
  __hip_bfloat16 h = __float2bfloat16(f);
  ushort u; __builtin_memcpy(&u, &h, 2); return u;
}

// async global->LDS, 16B per lane. LDS dest must be wave-uniform base +
// lane*16 (m104/m108); staging index c = ph*256 + w*64 + lane satisfies it.
__device__ __forceinline__ void gld_lds16(const void* g, void* l) {
  auto gp = (const __attribute__((address_space(1))) void*)(uintptr_t)(g);
  auto lp = (__attribute__((address_space(3))) void*)(uintptr_t)(l);
  __builtin_amdgcn_global_load_lds(gp, lp, 16, 0, 0);
}

// XCD-chunked bijective block swizzle. Requires gridDim.x*y*z % 8 == 0
// (holds: 1536 / 1024 / 512 / 512). flat <-> swz is bijective:
// swz = (flat&7)*chunk + (flat>>3), flat>>3 in [0,chunk).
#define SWZ_BLOCK()                                                     \
  int bx, by, bz;                                                       \
  {                                                                     \
    int nbx = gridDim.x, nby = gridDim.y;                               \
    int flat = blockIdx.x + nbx * (blockIdx.y + nby * blockIdx.z);      \
    int chunk = (nbx * nby * (int)gridDim.z) >> 3;                      \
    int swz = (flat & 7) * chunk + (flat >> 3);                         \
    bx = swz % nbx; int t_ = swz / nbx;                                 \
    by = t_ % nby; bz = t_ / nby;                                       \
  }

// ---------------- fused prep: GN stats | proj_weight+I | qkv_weight cvt ----
// Block-uniform branch on blockIdx.x ranges.
__global__ __launch_bounds__(256) void prep_k(
    const float* __restrict__ x, const float* __restrict__ gw,
    const float* __restrict__ gb, float* __restrict__ scale,
    float* __restrict__ shift, const float* __restrict__ pw,
    ushort* __restrict__ pwI, const float* __restrict__ wqkv_f,
    ushort* __restrict__ wqkv) {
  __shared__ float sb[4], ssb[4];
  int blk = blockIdx.x;
  if (blk < 512) {  // ---- GN stats: b = blk>>5, g = blk&31
    int b = blk >> 5, g = blk & 31;
    const float* xp = x + ((size_t)b * 512 + g * 16) * 1024;
    float s = 0.f, ss = 0.f;
    for (int i = threadIdx.x; i < 4096; i += 256) {
      float4 u = ((const float4*)xp)[i];
      s += u.x + u.y + u.z + u.w;
      ss += u.x * u.x + u.y * u.y + u.z * u.z + u.w * u.w;
    }
#pragma unroll
    for (int off = 32; off >= 1; off >>= 1) {
      s += __shfl_xor(s, off); ss += __shfl_xor(ss, off);
    }
    int w = threadIdx.x >> 6;
    if ((threadIdx.x & 63) == 0) { sb[w] = s; ssb[w] = ss; }
    __syncthreads();
    float st = sb[0] + sb[1] + sb[2] + sb[3];
    float sst = ssb[0] + ssb[1] + ssb[2] + ssb[3];
    float mean = st * (1.f / 16384.f);
    float var = sst * (1.f / 16384.f) - mean * mean;
    float rstd = rsqrtf(var + 1e-5f);
    if (threadIdx.x < 16) {
      int c = g * 16 + threadIdx.x;
      float wc = gw[c];
      scale[b * 512 + c] = rstd * wc;
      shift[b * 512 + c] = gb[c] - mean * rstd * wc;
    }
  } else if (blk < 1536) {  // ---- pwI = bf16(proj_weight + I), 262144 elems
    int i = (blk - 512) * 256 + threadIdx.x;
    int r = i >> 9, c = i & 511;
    pwI[i] = f2b(pw[i] + (r == c ? 1.f : 0.f));
  } else {  // ---- wqkv bf16 convert, 786432 elems, blocks 1536..4607
    int i = (blk - 1536) * 256 + threadIdx.x;
    wqkv[i] = f2b(wqkv_f[i]);
  }
}

// ---------------- normalize + transpose: xn_t[b][n][c] (bf16) ----------------
__global__ __launch_bounds__(256) void xn_t_k(
    const float* __restrict__ x, const float* __restrict__ scale,
    const float* __restrict__ shift, ushort* __restrict__ xt) {
  int b = blockIdx.z, c0 = blockIdx.y * 64, n0 = blockIdx.x * 64;
  __shared__ ushort tile[64][65];
  const float* xp = x + ((size_t)b * 512 + c0) * 1024 + n0;
  int t = threadIdx.x;
  int nq = t & 15, cr = t >> 4;
#pragma unroll
  for (int p = 0; p < 4; ++p) {
    int c = cr + p * 16;
    float4 v = *(const float4*)(xp + (size_t)c * 1024 + nq * 4);
    float sc = scale[b * 512 + c0 + c], sh = shift[b * 512 + c0 + c];
    tile[c][nq * 4 + 0] = f2b(v.x * sc + sh);
    tile[c][nq * 4 + 1] = f2b(v.y * sc + sh);
    tile[c][nq * 4 + 2] = f2b(v.z * sc + sh);
    tile[c][nq * 4 + 3] = f2b(v.w * sc + sh);
  }
  __syncthreads();
  ushort* op = xt + ((size_t)b * 1024 + n0) * 512 + c0;
  int cq = t & 15, nr = t >> 4;
#pragma unroll
  for (int p = 0; p < 4; ++p) {
    int n = nr + p * 16;
    ushort4 u;
    u.x = tile[cq * 4 + 0][n]; u.y = tile[cq * 4 + 1][n];
    u.z = tile[cq * 4 + 2][n]; u.w = tile[cq * 4 + 3][n];
    *(ushort4*)(op + (size_t)n * 512 + cq * 4) = u;
  }
}

// ---------------- shared 128x128 GEMM core: C = A[M][K] . B[N][K]^T ----------
// 256 threads = 4 waves in 2x2; each wave 64x64 via 4x4 mfma_f32_16x16x32_bf16.
// A-frag: m=lane&15, k=(lane>>4)*8+j ; B-frag: n=lane&15, same k (doc-verified).
// Triple-buffered (3 x 8KB per matrix), 2 tiles in flight, one raw barrier
// per K-iter with s_waitcnt vmcnt(4). K templated -> full unroll, constant
// buffer rotation and addresses.
template <int K>
__device__ __forceinline__ void gemm128(const ushort* __restrict__ Ag, int lda,
                                        const ushort* __restrict__ Bg, int ldb,
                                        f32x4 (&acc)[4][4], ushort* As,
                                        ushort* Bs) {
  const int t = threadIdx.x;
  const int lane = t & 63, w = t >> 6;
  const int wm = (w >> 1) * 64, wn = (w & 1) * 64;
  const int fr = lane & 15;
  const int fk = (lane >> 4) * 8;
  constexpr int nIter = K >> 5;

  auto stage = [&](int tile) {
    int buf = (tile % 3) * 4096;  // ushort offset: 8KB per buffer
    int k0 = tile * 32;
#pragma unroll
    for (int ph = 0; ph < 2; ++ph) {
      int c = ph * 256 + t;
      int r = c >> 2, kc = (c & 3) * 8;
      gld_lds16(Ag + (size_t)r * lda + k0 + kc, As + buf + c * 8);
      gld_lds16(Bg + (size_t)r * ldb + k0 + kc, Bs + buf + c * 8);
    }
  };

  stage(0);
  stage(1);  // 8 loads/thread in flight
#pragma unroll
  for (int it = 0; it < nIter; ++it) {
    // Wait only for the oldest stage (the tile we're about to consume);
    // the newer stage (<=4 ops) stays in flight across the barrier.
    if (it + 1 < nIter) {
      asm volatile("s_waitcnt vmcnt(4)" ::: "memory");
    } else {
      asm volatile("s_waitcnt vmcnt(0)" ::: "memory");
    }
    __builtin_amdgcn_s_barrier();
    asm volatile("" ::: "memory");
    if (it + 2 < nIter) stage(it + 2);  // async into buf[(it+2)%3]
    const int buf = (it % 3) * 4096;
    bf16x8 af[4], bfr[4];
#pragma unroll
    for (int i = 0; i < 4; ++i)
      af[i] = *(const bf16x8*)(As + buf + (wm + i * 16 + fr) * 32 + fk);
#pragma unroll
    for (int j = 0; j < 4; ++j)
      bfr[j] = *(const bf16x8*)(Bs + buf + (wn + j * 16 + fr) * 32 + fk);
#pragma unroll
    for (int i = 0; i < 4; ++i)
#pragma unroll
      for (int j = 0; j < 4; ++j)
        acc[i][j] = __builtin_amdgcn_mfma_f32_16x16x32_bf16(af[i], bfr[j],
                                                            acc[i][j], 0, 0, 0);
  }
}

#define GEMM_PROLOGUE()                                        \
  __shared__ ushort As[12288], Bs[12288];                      \
  f32x4 acc[4][4];                                             \
  { f32x4 z = {0.f, 0.f, 0.f, 0.f};                            \
    _Pragma("unroll") for (int i = 0; i < 4; ++i)              \
      _Pragma("unroll") for (int j = 0; j < 4; ++j) acc[i][j] = z; }

#define EPILOGUE_IDX()                                         \
  int lane = threadIdx.x & 63, w = threadIdx.x >> 6;           \
  int wm = (w >> 1) * 64, wn = (w & 1) * 64;                   \
  int ml = (lane >> 4) * 4, nl = lane & 15;

// ---------------- QKV GEMM ----------------
// q/k o-tiles (n0<1024): D[n][o] = xt . wqkv^T  -> qk[b][n][o]
// v  o-tiles (n0>=1024): operands swapped: D[c][m] = wqkv . xt^T -> v[b][c][m]
__global__ __launch_bounds__(256) void gemm_qkv_k(
    const ushort* __restrict__ xt, const ushort* __restrict__ wqkv,
    const float* __restrict__ bias, ushort* __restrict__ qk,
    ushort* __restrict__ v) {
  SWZ_BLOCK();
  int b = bz;
  int m0 = bx * 128;  // n-position
  int n0 = by * 128;  // output channel (0..1536)
  GEMM_PROLOGUE();
  const ushort* Xg = xt + ((size_t)b * 1024 + m0) * 512;
  const ushort* Wg = wqkv + (size_t)n0 * 512;
  const bool isv = (n0 >= 1024);
  if (!isv)
    gemm128<512>(Xg, 512, Wg, 512, acc, As, Bs);
  else
    gemm128<512>(Wg, 512, Xg, 512, acc, As, Bs);
  EPILOGUE_IDX();
  const float qscale = 0.044194173824159216f;  // 512^-0.5
  if (!isv) {
#pragma unroll
    for (int i = 0; i < 4; ++i)
#pragma unroll
      for (int j = 0; j < 4; ++j) {
        int gn = n0 + wn + j * 16 + nl;  // o-channel
        float bs = bias[gn];
        float sc = (gn < 512) ? qscale : 1.f;
#pragma unroll
        for (int r = 0; r < 4; ++r) {
          int gm = m0 + wm + i * 16 + ml + r;  // n-position
          qk[((size_t)b * 1024 + gm) * 1024 + gn] = f2b((acc[i][j][r] + bs) * sc);
        }
      }
  } else {
#pragma unroll
    for (int i = 0; i < 4; ++i)
#pragma unroll
      for (int j = 0; j < 4; ++j)
#pragma unroll
        for (int r = 0; r < 4; ++r) {
          int c = n0 + wm + i * 16 + ml + r;  // o-channel (1024..1536)
          int m = m0 + wn + j * 16 + nl;      // n-position (coalesced)
          v[((size_t)b * 512 + (c - 1024)) * 1024 + m] =
              f2b(acc[i][j][r] + bias[c]);
        }
  }
}

// ---------------- S GEMM: S[n][m] = q_t . k_t^T ----------------
__global__ __launch_bounds__(256) void gemm_s_k(const ushort* __restrict__ qk,
                                                ushort* __restrict__ S) {
  SWZ_BLOCK();
  int b = bz;
  int m0 = bx * 128, n0 = by * 128;
  GEMM_PROLOGUE();
  const ushort* Ag = qk + ((size_t)b * 1024 + m0) * 1024;        // q cols 0..512
  const ushort* Bg = qk + ((size_t)b * 1024 + n0) * 1024 + 512;  // k cols 512..1024
  gemm128<512>(Ag, 1024, Bg, 1024, acc, As, Bs);
  EPILOGUE_IDX();
#pragma unroll
  for (int i = 0; i < 4; ++i)
#pragma unroll
    for (int j = 0; j < 4; ++j)
#pragma unroll
      for (int r = 0; r < 4; ++r) {
        int gm = m0 + wm + i * 16 + ml + r, gn = n0 + wn + j * 16 + nl;
        S[((size_t)b * 1024 + gm) * 1024 + gn] = f2b(acc[i][j][r]);
      }
}

// ---------------- rowwise softmax in place (wave per row, bf16) ----------------
__global__ __launch_bounds__(256) void softmax_k(ushort* __restrict__ S) {
  int row = blockIdx.x * 4 + (threadIdx.x >> 6);
  int lane = threadIdx.x & 63;
  ushort* p = S + (size_t)row * 1024 + lane * 16;
  uint4 u0 = *(uint4*)p, u1 = *(uint4*)(p + 8);
  float v[16];
  const ushort* e0 = (const ushort*)&u0;
  const ushort* e1 = (const ushort*)&u1;
#pragma unroll
  for (int j = 0; j < 8; ++j) { v[j] = b2f(e0[j]); v[8 + j] = b2f(e1[j]); }
  float m = v[0];
#pragma unroll
  for (int j = 1; j < 16; ++j) m = fmaxf(m, v[j]);
#pragma unroll
  for (int off = 32; off >= 1; off >>= 1) m = fmaxf(m, __shfl_xor(m, off));
  float s = 0.f;
#pragma unroll
  for (int j = 0; j < 16; ++j) { v[j] = __expf(v[j] - m); s += v[j]; }
#pragma unroll
  for (int off = 32; off >= 1; off >>= 1) s += __shfl_xor(s, off);
  float inv = 1.f / s;
  uint4 r4[2];
  ushort* r = (ushort*)r4;
#pragma unroll
  for (int j = 0; j < 16; ++j) r[j] = f2b(v[j] * inv);
  *(uint4*)p = r4[0];
  *(uint4*)(p + 8) = r4[1];
}

// ---------------- O GEMM: ot[n][c] = P . v^T ----------------
__global__ __launch_bounds__(256) void gemm_o_k(const ushort* __restrict__ S,
                                                const ushort* __restrict__ v,
                                                ushort* __restrict__ ot) {
  SWZ_BLOCK();
  int b = bz;
  int m0 = bx * 128;  // n-position
  int n0 = by * 128;  // channel (0..512)
  GEMM_PROLOGUE();
  const ushort* Ag = S + ((size_t)b * 1024 + m0) * 1024;
  const ushort* Bg = v + ((size_t)b * 512 + n0) * 1024;
  gemm128<1024>(Ag, 1024, Bg, 1024, acc, As, Bs);
  EPILOGUE_IDX();
#pragma unroll
  for (int i = 0; i < 4; ++i)
#pragma unroll
    for (int j = 0; j < 4; ++j)
#pragma unroll
      for (int r = 0; r < 4; ++r) {
        int gm = m0 + wm + i * 16 + ml + r, gn = n0 + wn + j * 16 + nl;
        ot[((size_t)b * 1024 + gm) * 512 + gn] = f2b(acc[i][j][r]);
      }
}

// ---------------- proj GEMM: out[o][n] = (Wp+I) . ot^T + bias (fp32 out) ----
__global__ __launch_bounds__(256) void gemm_proj_k(
    const ushort* __restrict__ pwI, const ushort* __restrict__ ot,
    const float* __restrict__ pb, float* __restrict__ out) {
  SWZ_BLOCK();
  int b = bz;
  int m0 = bx * 128;  // o-channel (0..512)
  int n0 = by * 128;  // n-position
  GEMM_PROLOGUE();
  const ushort* Ag = pwI + (size_t)m0 * 512;
  const ushort* Bg = ot + ((size_t)b * 1024 + n0) * 512;
  gemm128<512>(Ag, 512, Bg, 512, acc, As, Bs);
  EPILOGUE_IDX();
#pragma unroll
  for (int i = 0; i < 4; ++i)
#pragma unroll
    for (int j = 0; j < 4; ++j)
#pragma unroll
      for (int r = 0; r < 4; ++r) {
        int gm = m0 + wm + i * 16 + ml + r;  // o-channel
        int gn = n0 + wn + j * 16 + nl;      // n-position
        out[((size_t)b * 512 + gm) * 1024 + gn] = acc[i][j][r] + pb[gm];
      }
}

extern "C" void kernel_launch(void* const* d_in, const int* in_sizes, int n_in,
                              void* d_out, int out_size, void* d_ws,
                              size_t ws_size, hipStream_t stream) {
  const float* x = (const float*)d_in[0];
  const float* gw = (const float*)d_in[1];
  const float* gb = (const float*)d_in[2];
  const float* wqkv_f = (const float*)d_in[3];
  const float* bqkv = (const float*)d_in[4];
  const float* pw = (const float*)d_in[5];
  const float* pb = (const float*)d_in[6];
  float* out = (float*)d_out;

  // Workspace layout (84.5 MB peak, region reuse):
  //   0        scale (32KB)
  //   32768    shift (32KB)
  //   65536    pwI bf16 (512KB)
  //   589824   wqkv bf16 (1.5MB)  [1536*512*2]
  //   2162688  R1 (32MB): xt[b][n][c] bf16 (first 16MB); later S[b][n][m]
  //   35717120 R2 (32MB): qk[b][n][0..1024) bf16; later ot[b][n][c] (16MB)
  //   69271552 R3 (16MB): v[b][c][m] bf16
  char* ws = (char*)d_ws;
  float* scale = (float*)(ws + 0);
  float* shift = (float*)(ws + 32768);
  ushort* pwI = (ushort*)(ws + 65536);
  ushort* wqkv = (ushort*)(ws + 589824);
  ushort* xt = (ushort*)(ws + 2162688);
  ushort* S = xt;                       // S overwrites dead xt region
  ushort* qk = (ushort*)(ws + 35717120);
  ushort* ot = qk;                      // ot overwrites dead qk region
  ushort* v = (ushort*)(ws + 69271552);

  prep_k<<<dim3(4608), 256, 0, stream>>>(x, gw, gb, scale, shift, pw, pwI,
                                         wqkv_f, wqkv);
  xn_t_k<<<dim3(16, 8, 16), 256, 0, stream>>>(x, scale, shift, xt);
  gemm_qkv_k<<<dim3(8, 12, 16), 256, 0, stream>>>(xt, wqkv, bqkv, qk, v);
  gemm_s_k<<<dim3(8, 8, 16), 256, 0, stream>>>(qk, S);
  softmax_k<<<dim3(4096), 256, 0, stream>>>(S);
  gemm_o_k<<<dim3(8, 4, 16), 256, 0, stream>>>(S, v, ot);
  gemm_proj_k<<<dim3(4, 8, 16), 256, 0, stream>>>(pwI, ot, pb, out);
}

// Round 5
// 212.418 us; speedup vs baseline: 1.0674x; 1.0252x over previous
//
#include <hip/hip_runtime.h>
#include <hip/hip_bf16.h>

// Problem: B=16, C=512, H=W=32 (N=1024), 32 groups (16 ch/group).
// Wire dtype: fp32; internal GEMM dtype: bf16.
// R9->R10: LDS bank-conflict fix in gemm128 (T2-class, adapted to 64B rows).
//   Old layout: fragment ds_read_b128 had any 8 consecutive lanes hitting
//   only 2 of 8 bank-quad groups (start = 16*(row&1) + 4*kq, kq uniform per
//   quarter-wave) -> ~4-way serialization. New: chunk position within each
//   64B row XOR-swizzled by (row>>1)&3. Staging pre-permutes the GLOBAL
//   source chunk (same 64B segment, lane-permuted -> coalescing intact) and
//   keeps the LDS dest linear (global_load_lds requirement, m104); reads
//   apply the same XOR. Every 8-lane beat now covers all 8 bank groups.
//   Bit-exact data movement; zero sync/structure delta vs R9 (217.8us).

typedef __attribute__((ext_vector_type(8))) short bf16x8;   // 8 bf16 = 4 VGPRs
typedef __attribute__((ext_vector_type(4))) float f32x4;

__device__ __forceinline__ float b2f(ushort u) {
  unsigned int v = ((unsigned int)u) << 16;
  float f; __builtin_memcpy(&f, &v, 4); return f;
}
__device__ __forceinline__ ushort f2b(float f) {
  __hip_bfloat16 h = __float2bfloat16(f);
  ushort u; __builtin_memcpy(&u, &h, 2); return u;
}

// async global->LDS, 16B per lane. LDS dest must be wave-uniform base +
// lane*16 (m104/m108); staging index c = ph*256 + w*64 + lane satisfies it.
__device__ __forceinline__ void gld_lds16(const void* g, void* l) {
  auto gp = (const __attribute__((address_space(1))) void*)(uintptr_t)(g);
  auto lp = (__attribute__((address_space(3))) void*)(uintptr_t)(l);
  __builtin_amdgcn_global_load_lds(gp, lp, 16, 0, 0);
}

// XCD-chunked bijective block swizzle. Requires gridDim.x*y*z % 8 == 0
// (holds: 1536 / 1024 / 512 / 512). flat <-> swz is bijective:
// swz = (flat&7)*chunk + (flat>>3), flat>>3 in [0,chunk).
#define SWZ_BLOCK()                                                     \
  int bx, by, bz;                                                       \
  {                                                                     \
    int nbx = gridDim.x, nby = gridDim.y;                               \
    int flat = blockIdx.x + nbx * (blockIdx.y + nby * blockIdx.z);      \
    int chunk = (nbx * nby * (int)gridDim.z) >> 3;                      \
    int swz = (flat & 7) * chunk + (flat >> 3);                         \
    bx = swz % nbx; int t_ = swz / nbx;                                 \
    by = t_ % nby; bz = t_ / nby;                                       \
  }

// ---------------- fused prep: GN stats | proj_weight+I | qkv_weight cvt ----
// Block-uniform branch on blockIdx.x ranges.
__global__ __launch_bounds__(256) void prep_k(
    const float* __restrict__ x, const float* __restrict__ gw,
    const float* __restrict__ gb, float* __restrict__ scale,
    float* __restrict__ shift, const float* __restrict__ pw,
    ushort* __restrict__ pwI, const float* __restrict__ wqkv_f,
    ushort* __restrict__ wqkv) {
  __shared__ float sb[4], ssb[4];
  int blk = blockIdx.x;
  if (blk < 512) {  // ---- GN stats: b = blk>>5, g = blk&31
    int b = blk >> 5, g = blk & 31;
    const float* xp = x + ((size_t)b * 512 + g * 16) * 1024;
    float s = 0.f, ss = 0.f;
    for (int i = threadIdx.x; i < 4096; i += 256) {
      float4 u = ((const float4*)xp)[i];
      s += u.x + u.y + u.z + u.w;
      ss += u.x * u.x + u.y * u.y + u.z * u.z + u.w * u.w;
    }
#pragma unroll
    for (int off = 32; off >= 1; off >>= 1) {
      s += __shfl_xor(s, off); ss += __shfl_xor(ss, off);
    }
    int w = threadIdx.x >> 6;
    if ((threadIdx.x & 63) == 0) { sb[w] = s; ssb[w] = ss; }
    __syncthreads();
    float st = sb[0] + sb[1] + sb[2] + sb[3];
    float sst = ssb[0] + ssb[1] + ssb[2] + ssb[3];
    float mean = st * (1.f / 16384.f);
    float var = sst * (1.f / 16384.f) - mean * mean;
    float rstd = rsqrtf(var + 1e-5f);
    if (threadIdx.x < 16) {
      int c = g * 16 + threadIdx.x;
      float wc = gw[c];
      scale[b * 512 + c] = rstd * wc;
      shift[b * 512 + c] = gb[c] - mean * rstd * wc;
    }
  } else if (blk < 1536) {  // ---- pwI = bf16(proj_weight + I), 262144 elems
    int i = (blk - 512) * 256 + threadIdx.x;
    int r = i >> 9, c = i & 511;
    pwI[i] = f2b(pw[i] + (r == c ? 1.f : 0.f));
  } else {  // ---- wqkv bf16 convert, 786432 elems, blocks 1536..4607
    int i = (blk - 1536) * 256 + threadIdx.x;
    wqkv[i] = f2b(wqkv_f[i]);
  }
}

// ---------------- normalize + transpose: xn_t[b][n][c] (bf16) ----------------
__global__ __launch_bounds__(256) void xn_t_k(
    const float* __restrict__ x, const float* __restrict__ scale,
    const float* __restrict__ shift, ushort* __restrict__ xt) {
  int b = blockIdx.z, c0 = blockIdx.y * 64, n0 = blockIdx.x * 64;
  __shared__ ushort tile[64][65];
  const float* xp = x + ((size_t)b * 512 + c0) * 1024 + n0;
  int t = threadIdx.x;
  int nq = t & 15, cr = t >> 4;
#pragma unroll
  for (int p = 0; p < 4; ++p) {
    int c = cr + p * 16;
    float4 v = *(const float4*)(xp + (size_t)c * 1024 + nq * 4);
    float sc = scale[b * 512 + c0 + c], sh = shift[b * 512 + c0 + c];
    tile[c][nq * 4 + 0] = f2b(v.x * sc + sh);
    tile[c][nq * 4 + 1] = f2b(v.y * sc + sh);
    tile[c][nq * 4 + 2] = f2b(v.z * sc + sh);
    tile[c][nq * 4 + 3] = f2b(v.w * sc + sh);
  }
  __syncthreads();
  ushort* op = xt + ((size_t)b * 1024 + n0) * 512 + c0;
  int cq = t & 15, nr = t >> 4;
#pragma unroll
  for (int p = 0; p < 4; ++p) {
    int n = nr + p * 16;
    ushort4 u;
    u.x = tile[cq * 4 + 0][n]; u.y = tile[cq * 4 + 1][n];
    u.z = tile[cq * 4 + 2][n]; u.w = tile[cq * 4 + 3][n];
    *(ushort4*)(op + (size_t)n * 512 + cq * 4) = u;
  }
}

// ---------------- shared 128x128 GEMM core: C = A[M][K] . B[N][K]^T ----------
// 256 threads = 4 waves in 2x2; each wave 64x64 via 4x4 mfma_f32_16x16x32_bf16.
// A-frag: m=lane&15, k=(lane>>4)*8+j ; B-frag: n=lane&15, same k (doc-verified).
// Triple-buffered (3 x 8KB per matrix), 2 tiles in flight, one raw barrier
// per K-iter with s_waitcnt vmcnt(4). K templated -> full unroll.
// LDS chunk swizzle: 16B chunk at row r, position p holds global k-chunk
// p ^ ((r>>1)&3); readers XOR the same selector. Spreads each 8-lane beat
// of ds_read_b128 across all 8 bank-quad groups (was 2). Bit-exact.
template <int K>
__device__ __forceinline__ void gemm128(const ushort* __restrict__ Ag, int lda,
                                        const ushort* __restrict__ Bg, int ldb,
                                        f32x4 (&acc)[4][4], ushort* As,
                                        ushort* Bs) {
  const int t = threadIdx.x;
  const int lane = t & 63, w = t >> 6;
  const int wm = (w >> 1) * 64, wn = (w & 1) * 64;
  const int fr = lane & 15;
  const int kq = lane >> 4;            // k-chunk index 0..3 (8 ushorts each)
  const int rswz = (fr >> 1) & 3;      // read-side XOR selector (row-derived)
  constexpr int nIter = K >> 5;

  auto stage = [&](int tile) {
    int buf = (tile % 3) * 4096;  // ushort offset: 8KB per buffer
    int k0 = tile * 32;
#pragma unroll
    for (int ph = 0; ph < 2; ++ph) {
      int c = ph * 256 + t;
      int r = c >> 2;
      int kc = (c & 3) ^ ((r >> 1) & 3);  // global chunk for LDS position c&3
      gld_lds16(Ag + (size_t)r * lda + k0 + kc * 8, As + buf + c * 8);
      gld_lds16(Bg + (size_t)r * ldb + k0 + kc * 8, Bs + buf + c * 8);
    }
  };

  stage(0);
  stage(1);  // 8 loads/thread in flight
#pragma unroll
  for (int it = 0; it < nIter; ++it) {
    // Wait only for the oldest stage (the tile we're about to consume);
    // the newer stage (<=4 ops) stays in flight across the barrier.
    if (it + 1 < nIter) {
      asm volatile("s_waitcnt vmcnt(4)" ::: "memory");
    } else {
      asm volatile("s_waitcnt vmcnt(0)" ::: "memory");
    }
    __builtin_amdgcn_s_barrier();
    asm volatile("" ::: "memory");
    if (it + 2 < nIter) stage(it + 2);  // async into buf[(it+2)%3]
    const int buf = (it % 3) * 4096;
    const int ko = (kq ^ rswz) << 3;    // swizzled chunk offset (ushorts)
    bf16x8 af[4], bfr[4];
#pragma unroll
    for (int i = 0; i < 4; ++i)
      af[i] = *(const bf16x8*)(As + buf + (wm + i * 16 + fr) * 32 + ko);
#pragma unroll
    for (int j = 0; j < 4; ++j)
      bfr[j] = *(const bf16x8*)(Bs + buf + (wn + j * 16 + fr) * 32 + ko);
#pragma unroll
    for (int i = 0; i < 4; ++i)
#pragma unroll
      for (int j = 0; j < 4; ++j)
        acc[i][j] = __builtin_amdgcn_mfma_f32_16x16x32_bf16(af[i], bfr[j],
                                                            acc[i][j], 0, 0, 0);
  }
}

#define GEMM_PROLOGUE()                                        \
  __shared__ ushort As[12288], Bs[12288];                      \
  f32x4 acc[4][4];                                             \
  { f32x4 z = {0.f, 0.f, 0.f, 0.f};                            \
    _Pragma("unroll") for (int i = 0; i < 4; ++i)              \
      _Pragma("unroll") for (int j = 0; j < 4; ++j) acc[i][j] = z; }

#define EPILOGUE_IDX()                                         \
  int lane = threadIdx.x & 63, w = threadIdx.x >> 6;           \
  int wm = (w >> 1) * 64, wn = (w & 1) * 64;                   \
  int ml = (lane >> 4) * 4, nl = lane & 15;

// ---------------- QKV GEMM ----------------
// q/k o-tiles (n0<1024): D[n][o] = xt . wqkv^T  -> qk[b][n][o]
// v  o-tiles (n0>=1024): operands swapped: D[c][m] = wqkv . xt^T -> v[b][c][m]
__global__ __launch_bounds__(256) void gemm_qkv_k(
    const ushort* __restrict__ xt, const ushort* __restrict__ wqkv,
    const float* __restrict__ bias, ushort* __restrict__ qk,
    ushort* __restrict__ v) {
  SWZ_BLOCK();
  int b = bz;
  int m0 = bx * 128;  // n-position
  int n0 = by * 128;  // output channel (0..1536)
  GEMM_PROLOGUE();
  const ushort* Xg = xt + ((size_t)b * 1024 + m0) * 512;
  const ushort* Wg = wqkv + (size_t)n0 * 512;
  const bool isv = (n0 >= 1024);
  if (!isv)
    gemm128<512>(Xg, 512, Wg, 512, acc, As, Bs);
  else
    gemm128<512>(Wg, 512, Xg, 512, acc, As, Bs);
  EPILOGUE_IDX();
  const float qscale = 0.044194173824159216f;  // 512^-0.5
  if (!isv) {
#pragma unroll
    for (int i = 0; i < 4; ++i)
#pragma unroll
      for (int j = 0; j < 4; ++j) {
        int gn = n0 + wn + j * 16 + nl;  // o-channel
        float bs = bias[gn];
        float sc = (gn < 512) ? qscale : 1.f;
#pragma unroll
        for (int r = 0; r < 4; ++r) {
          int gm = m0 + wm + i * 16 + ml + r;  // n-position
          qk[((size_t)b * 1024 + gm) * 1024 + gn] = f2b((acc[i][j][r] + bs) * sc);
        }
      }
  } else {
#pragma unroll
    for (int i = 0; i < 4; ++i)
#pragma unroll
      for (int j = 0; j < 4; ++j)
#pragma unroll
        for (int r = 0; r < 4; ++r) {
          int c = n0 + wm + i * 16 + ml + r;  // o-channel (1024..1536)
          int m = m0 + wn + j * 16 + nl;      // n-position (coalesced)
          v[((size_t)b * 512 + (c - 1024)) * 1024 + m] =
              f2b(acc[i][j][r] + bias[c]);
        }
  }
}

// ---------------- S GEMM: S[n][m] = q_t . k_t^T ----------------
__global__ __launch_bounds__(256) void gemm_s_k(const ushort* __restrict__ qk,
                                                ushort* __restrict__ S) {
  SWZ_BLOCK();
  int b = bz;
  int m0 = bx * 128, n0 = by * 128;
  GEMM_PROLOGUE();
  const ushort* Ag = qk + ((size_t)b * 1024 + m0) * 1024;        // q cols 0..512
  const ushort* Bg = qk + ((size_t)b * 1024 + n0) * 1024 + 512;  // k cols 512..1024
  gemm128<512>(Ag, 1024, Bg, 1024, acc, As, Bs);
  EPILOGUE_IDX();
#pragma unroll
  for (int i = 0; i < 4; ++i)
#pragma unroll
    for (int j = 0; j < 4; ++j)
#pragma unroll
      for (int r = 0; r < 4; ++r) {
        int gm = m0 + wm + i * 16 + ml + r, gn = n0 + wn + j * 16 + nl;
        S[((size_t)b * 1024 + gm) * 1024 + gn] = f2b(acc[i][j][r]);
      }
}

// ---------------- rowwise softmax in place (wave per row, bf16) ----------------
__global__ __launch_bounds__(256) void softmax_k(ushort* __restrict__ S) {
  int row = blockIdx.x * 4 + (threadIdx.x >> 6);
  int lane = threadIdx.x & 63;
  ushort* p = S + (size_t)row * 1024 + lane * 16;
  uint4 u0 = *(uint4*)p, u1 = *(uint4*)(p + 8);
  float v[16];
  const ushort* e0 = (const ushort*)&u0;
  const ushort* e1 = (const ushort*)&u1;
#pragma unroll
  for (int j = 0; j < 8; ++j) { v[j] = b2f(e0[j]); v[8 + j] = b2f(e1[j]); }
  float m = v[0];
#pragma unroll
  for (int j = 1; j < 16; ++j) m = fmaxf(m, v[j]);
#pragma unroll
  for (int off = 32; off >= 1; off >>= 1) m = fmaxf(m, __shfl_xor(m, off));
  float s = 0.f;
#pragma unroll
  for (int j = 0; j < 16; ++j) { v[j] = __expf(v[j] - m); s += v[j]; }
#pragma unroll
  for (int off = 32; off >= 1; off >>= 1) s += __shfl_xor(s, off);
  float inv = 1.f / s;
  uint4 r4[2];
  ushort* r = (ushort*)r4;
#pragma unroll
  for (int j = 0; j < 16; ++j) r[j] = f2b(v[j] * inv);
  *(uint4*)p = r4[0];
  *(uint4*)(p + 8) = r4[1];
}

// ---------------- O GEMM: ot[n][c] = P . v^T ----------------
__global__ __launch_bounds__(256) void gemm_o_k(const ushort* __restrict__ S,
                                                const ushort* __restrict__ v,
                                                ushort* __restrict__ ot) {
  SWZ_BLOCK();
  int b = bz;
  int m0 = bx * 128;  // n-position
  int n0 = by * 128;  // channel (0..512)
  GEMM_PROLOGUE();
  const ushort* Ag = S + ((size_t)b * 1024 + m0) * 1024;
  const ushort* Bg = v + ((size_t)b * 512 + n0) * 1024;
  gemm128<1024>(Ag, 1024, Bg, 1024, acc, As, Bs);
  EPILOGUE_IDX();
#pragma unroll
  for (int i = 0; i < 4; ++i)
#pragma unroll
    for (int j = 0; j < 4; ++j)
#pragma unroll
      for (int r = 0; r < 4; ++r) {
        int gm = m0 + wm + i * 16 + ml + r, gn = n0 + wn + j * 16 + nl;
        ot[((size_t)b * 1024 + gm) * 512 + gn] = f2b(acc[i][j][r]);
      }
}

// ---------------- proj GEMM: out[o][n] = (Wp+I) . ot^T + bias (fp32 out) ----
__global__ __launch_bounds__(256) void gemm_proj_k(
    const ushort* __restrict__ pwI, const ushort* __restrict__ ot,
    const float* __restrict__ pb, float* __restrict__ out) {
  SWZ_BLOCK();
  int b = bz;
  int m0 = bx * 128;  // o-channel (0..512)
  int n0 = by * 128;  // n-position
  GEMM_PROLOGUE();
  const ushort* Ag = pwI + (size_t)m0 * 512;
  const ushort* Bg = ot + ((size_t)b * 1024 + n0) * 512;
  gemm128<512>(Ag, 512, Bg, 512, acc, As, Bs);
  EPILOGUE_IDX();
#pragma unroll
  for (int i = 0; i < 4; ++i)
#pragma unroll
    for (int j = 0; j < 4; ++j)
#pragma unroll
      for (int r = 0; r < 4; ++r) {
        int gm = m0 + wm + i * 16 + ml + r;  // o-channel
        int gn = n0 + wn + j * 16 + nl;      // n-position
        out[((size_t)b * 512 + gm) * 1024 + gn] = acc[i][j][r] + pb[gm];
      }
}

extern "C" void kernel_launch(void* const* d_in, const int* in_sizes, int n_in,
                              void* d_out, int out_size, void* d_ws,
                              size_t ws_size, hipStream_t stream) {
  const float* x = (const float*)d_in[0];
  const float* gw = (const float*)d_in[1];
  const float* gb = (const float*)d_in[2];
  const float* wqkv_f = (const float*)d_in[3];
  const float* bqkv = (const float*)d_in[4];
  const float* pw = (const float*)d_in[5];
  const float* pb = (const float*)d_in[6];
  float* out = (float*)d_out;

  // Workspace layout (84.5 MB peak, region reuse):
  //   0        scale (32KB)
  //   32768    shift (32KB)
  //   65536    pwI bf16 (512KB)
  //   589824   wqkv bf16 (1.5MB)  [1536*512*2]
  //   2162688  R1 (32MB): xt[b][n][c] bf16 (first 16MB); later S[b][n][m]
  //   35717120 R2 (32MB): qk[b][n][0..1024) bf16; later ot[b][n][c] (16MB)
  //   69271552 R3 (16MB): v[b][c][m] bf16
  char* ws = (char*)d_ws;
  float* scale = (float*)(ws + 0);
  float* shift = (float*)(ws + 32768);
  ushort* pwI = (ushort*)(ws + 65536);
  ushort* wqkv = (ushort*)(ws + 589824);
  ushort* xt = (ushort*)(ws + 2162688);
  ushort* S = xt;                       // S overwrites dead xt region
  ushort* qk = (ushort*)(ws + 35717120);
  ushort* ot = qk;                      // ot overwrites dead qk region
  ushort* v = (ushort*)(ws + 69271552);

  prep_k<<<dim3(4608), 256, 0, stream>>>(x, gw, gb, scale, shift, pw, pwI,
                                         wqkv_f, wqkv);
  xn_t_k<<<dim3(16, 8, 16), 256, 0, stream>>>(x, scale, shift, xt);
  gemm_qkv_k<<<dim3(8, 12, 16), 256, 0, stream>>>(xt, wqkv, bqkv, qk, v);
  gemm_s_k<<<dim3(8, 8, 16), 256, 0, stream>>>(qk, S);
  softmax_k<<<dim3(4096), 256, 0, stream>>>(S);
  gemm_o_k<<<dim3(8, 4, 16), 256, 0, stream>>>(S, v, ot);
  gemm_proj_k<<<dim3(4, 8, 16), 256, 0, stream>>>(pwI, ot, pb, out);
}